// Round 1
// baseline (590.341 us; speedup 1.0000x reference)
//
#include <hip/hip_runtime.h>
#include <math.h>

#define BB 8
#define QQ 100
#define CC 41
#define TT 50
#define HH 256
#define WW 256
#define PP 12544   // = 49 * 256 exactly
#define TCH 25

// Bilinear sample matching F.grid_sample(align_corners=False, padding_mode='zeros')
__device__ __forceinline__ float bilin(const float* __restrict__ m, float cx, float cy) {
    float x = cx * WW - 0.5f;
    float y = cy * HH - 0.5f;
    float x0f = floorf(x), y0f = floorf(y);
    float wx = x - x0f, wy = y - y0f;
    int x0 = (int)x0f, y0 = (int)y0f;
    int x1 = x0 + 1, y1 = y0 + 1;
    float fx0 = (x0 >= 0 && x0 < WW) ? 1.f : 0.f;
    float fx1 = (x1 >= 0 && x1 < WW) ? 1.f : 0.f;
    float fy0 = (y0 >= 0 && y0 < HH) ? 1.f : 0.f;
    float fy1 = (y1 >= 0 && y1 < HH) ? 1.f : 0.f;
    int x0c = min(max(x0, 0), WW - 1);
    int x1c = min(max(x1, 0), WW - 1);
    int y0c = min(max(y0, 0), HH - 1);
    int y1c = min(max(y1, 0), HH - 1);
    float v00 = m[y0c * WW + x0c] * (fx0 * fy0);
    float v01 = m[y0c * WW + x1c] * (fx1 * fy0);
    float v10 = m[y1c * WW + x0c] * (fx0 * fy1);
    float v11 = m[y1c * WW + x1c] * (fx1 * fy1);
    return v00 * (1.f - wx) * (1.f - wy) + v01 * wx * (1.f - wy)
         + v10 * (1.f - wx) * wy + v11 * wx * wy;
}

// One block per (b,t): sample tgt mask at the batch's points -> tm row + tmsum
__global__ __launch_bounds__(256) void sample_tm_kernel(
    const float* __restrict__ tgt_masks, const float* __restrict__ coords,
    float* __restrict__ tm, float* __restrict__ tmsum)
{
    int bt = blockIdx.x;            // b*TT + t
    int b = bt / TT;
    const float* m = tgt_masks + (size_t)bt * (HH * WW);
    const float2* cd = (const float2*)coords + (size_t)b * PP;
    float ls = 0.f;
    for (int p = threadIdx.x; p < PP; p += 256) {
        float2 c = cd[p];
        float v = bilin(m, c.x, c.y);
        tm[(size_t)bt * PP + p] = v;
        ls += v;
    }
    __shared__ float red[4];
    #pragma unroll
    for (int off = 32; off; off >>= 1) ls += __shfl_down(ls, off, 64);
    if ((threadIdx.x & 63) == 0) red[threadIdx.x >> 6] = ls;
    __syncthreads();
    if (threadIdx.x == 0) tmsum[bt] = red[0] + red[1] + red[2] + red[3];
}

// One block per (b,q): sample om row into LDS, compute negsum/ssum, then
// 50x2 dot products against tm[b] and the fused epilogue -> Cmat row.
__global__ __launch_bounds__(256) void cost_kernel(
    const float* __restrict__ pred_masks, const float* __restrict__ coords,
    const float* __restrict__ tm, const float* __restrict__ tmsum,
    const float* __restrict__ pred_logits, const float* __restrict__ pred_obj,
    const int* __restrict__ tgt_labels, float* __restrict__ out)
{
    __shared__ float om_lds[PP];          // 50,176 B
    __shared__ float red[4][2 * TCH];
    __shared__ float scal[2];
    int bq = blockIdx.x;                  // b*QQ + q
    int b = bq / QQ;
    const float* m = pred_masks + (size_t)bq * (HH * WW);
    const float2* cd = (const float2*)coords + (size_t)b * PP;
    int tid = threadIdx.x, lane = tid & 63, wv = tid >> 6;

    // --- phase 1: sample om into LDS, accumulate softplus/sigmoid sums ---
    float lneg = 0.f, lsig = 0.f;
    for (int p = tid; p < PP; p += 256) {
        float2 c = cd[p];
        float v = bilin(m, c.x, c.y);
        om_lds[p] = v;
        float em = __expf(-fabsf(v));
        lneg += fmaxf(v, 0.f) + __logf(1.f + em);          // softplus(v)
        lsig += (v >= 0.f) ? 1.f / (1.f + em) : em / (1.f + em);  // sigmoid(v)
    }
    #pragma unroll
    for (int off = 32; off; off >>= 1) {
        lneg += __shfl_down(lneg, off, 64);
        lsig += __shfl_down(lsig, off, 64);
    }
    if (lane == 0) { red[wv][0] = lneg; red[wv][1] = lsig; }
    __syncthreads();
    if (tid == 0) {
        scal[0] = red[0][0] + red[1][0] + red[2][0] + red[3][0];
        scal[1] = red[0][1] + red[1][1] + red[2][1] + red[3][1];
    }
    __syncthreads();

    const float* tmb = tm + (size_t)b * TT * PP;

    // --- phase 2: dots over P for all T targets (2 chunks of 25) ---
    for (int tc = 0; tc < 2; ++tc) {
        float acc_om[TCH], acc_s[TCH];
        #pragma unroll
        for (int i = 0; i < TCH; ++i) { acc_om[i] = 0.f; acc_s[i] = 0.f; }
        const float* tmc = tmb + (size_t)(tc * TCH) * PP;
        for (int p = tid; p < PP; p += 256) {
            float ov = om_lds[p];
            float em = __expf(-fabsf(ov));
            float sv = (ov >= 0.f) ? 1.f / (1.f + em) : em / (1.f + em);
            #pragma unroll
            for (int t = 0; t < TCH; ++t) {
                float tv = tmc[(size_t)t * PP + p];
                acc_om[t] = fmaf(ov, tv, acc_om[t]);
                acc_s[t]  = fmaf(sv, tv, acc_s[t]);
            }
        }
        #pragma unroll
        for (int t = 0; t < TCH; ++t) {
            float a = acc_om[t], s2 = acc_s[t];
            #pragma unroll
            for (int off = 32; off; off >>= 1) {
                a  += __shfl_down(a, off, 64);
                s2 += __shfl_down(s2, off, 64);
            }
            if (lane == 0) { red[wv][t] = a; red[wv][TCH + t] = s2; }
        }
        __syncthreads();
        if (tid < TCH) {
            int tg = tc * TCH + tid;
            float dot_om = red[0][tid] + red[1][tid] + red[2][tid] + red[3][tid];
            float dot_s  = red[0][TCH + tid] + red[1][TCH + tid]
                         + red[2][TCH + tid] + red[3][TCH + tid];
            float ns = scal[0], ss = scal[1];
            float ts = tmsum[b * TT + tg];
            float cmask = (ns - dot_om) * (1.f / PP);
            float cdice = 1.f - (2.f * dot_s + 1.f) / (ss + ts + 1.f);
            int label = tgt_labels[b * TT + tg];
            float a0 = pred_obj[bq * 2], a1 = pred_obj[bq * 2 + 1];
            float prob;
            if (label == CC - 1) {
                prob = 1.f / (1.f + __expf(a0 - a1));           // obj1
            } else {
                float pc = 1.f / (1.f + __expf(-pred_logits[(size_t)bq * CC + label]));
                float po = 1.f / (1.f + __expf(a1 - a0));       // obj0
                prob = sqrtf(pc * po);
            }
            out[(size_t)bq * TT + tg] = 5.f * cmask - 2.f * prob + 5.f * cdice;
        }
        __syncthreads();
    }
}

extern "C" void kernel_launch(void* const* d_in, const int* in_sizes, int n_in,
                              void* d_out, int out_size, void* d_ws, size_t ws_size,
                              hipStream_t stream) {
    const float* pred_logits = (const float*)d_in[0];   // [8,100,41]
    const float* pred_obj    = (const float*)d_in[1];   // [8,100,2]
    const float* pred_masks  = (const float*)d_in[2];   // [8,100,256,256]
    const float* tgt_masks   = (const float*)d_in[3];   // [8,50,256,256]
    const int*   tgt_labels  = (const int*)d_in[4];     // [8,50]
    const float* coords      = (const float*)d_in[5];   // [8,12544,2]
    float* out = (float*)d_out;                         // [8,100,50]

    float* tm    = (float*)d_ws;                        // BB*TT*PP floats (20.07 MB)
    float* tmsum = tm + (size_t)BB * TT * PP;           // BB*TT floats

    hipLaunchKernelGGL(sample_tm_kernel, dim3(BB * TT), dim3(256), 0, stream,
                       tgt_masks, coords, tm, tmsum);
    hipLaunchKernelGGL(cost_kernel, dim3(BB * QQ), dim3(256), 0, stream,
                       pred_masks, coords, tm, tmsum,
                       pred_logits, pred_obj, tgt_labels, out);
}